// Round 4
// baseline (1961.340 us; speedup 1.0000x reference)
//
#include <hip/hip_runtime.h>
#include <cstdint>

typedef unsigned short u16;
typedef __bf16 bf16x8 __attribute__((ext_vector_type(8)));
typedef float f32x4 __attribute__((ext_vector_type(4)));

#define LDS_STRIDE 40  // 32 + 8 pad shorts; row pitch 80B (16B-aligned)

__device__ __forceinline__ u16 f2bf(float f) {
    uint32_t u = __float_as_uint(f);
    u += 0x7FFFu + ((u >> 16) & 1u);
    return (u16)(u >> 16);
}
__device__ __forceinline__ float bf2f(u16 v) {
    return __uint_as_float((uint32_t)v << 16);
}

// ---------------------------------------------------------------------------
// Dtype detect: fp32 storage -> low-mantissa u16 words are uniform random ->
// max(bits&0x7FFF) ~ 0x7FFF. bf16 N(0,sigma) data stays < ~0x5000 unless
// |x| > 3.4e9. Writes mode flag (1=fp32, 0=bf16).
// ---------------------------------------------------------------------------
__global__ __launch_bounds__(256) void k_detect(const u16* __restrict__ x,
                                                int* __restrict__ flag) {
    const int t = threadIdx.x;
    uint32_t mx = 0;
    for (int i = 0; i < 256; i++) {
        uint32_t v = (uint32_t)x[i * 256 + t] & 0x7FFFu;
        mx = mx > v ? mx : v;
    }
    for (int off = 32; off > 0; off >>= 1) {
        uint32_t o = (uint32_t)__shfl_xor((int)mx, off);
        mx = mx > o ? mx : o;
    }
    __shared__ uint32_t r[4];
    if ((t & 63) == 0) r[t >> 6] = mx;
    __syncthreads();
    if (t == 0) {
        uint32_t a = r[0] > r[1] ? r[0] : r[1];
        uint32_t b = r[2] > r[3] ? r[2] : r[3];
        mx = a > b ? a : b;
        *flag = (mx > 0x5000u) ? 1 : 0;
    }
}

// ---------------------------------------------------------------------------
// Canonicalize x -> bf16 Xc. 8 elems/thread. grid 8192.
// ---------------------------------------------------------------------------
__global__ __launch_bounds__(256) void k_cvt_x(const void* __restrict__ src,
                                               const int* __restrict__ flag,
                                               u16* __restrict__ dst) {
    const int mode = *flag;
    size_t i0 = ((size_t)blockIdx.x * 256 + threadIdx.x) * 8;
    if (mode) {
        const float4* s = (const float4*)src;
        float4 a = s[i0 / 4], b = s[i0 / 4 + 1];
        uint32_t o0 = (uint32_t)f2bf(a.x) | ((uint32_t)f2bf(a.y) << 16);
        uint32_t o1 = (uint32_t)f2bf(a.z) | ((uint32_t)f2bf(a.w) << 16);
        uint32_t o2 = (uint32_t)f2bf(b.x) | ((uint32_t)f2bf(b.y) << 16);
        uint32_t o3 = (uint32_t)f2bf(b.z) | ((uint32_t)f2bf(b.w) << 16);
        *(uint4*)(dst + i0) = make_uint4(o0, o1, o2, o3);
    } else {
        *(uint4*)(dst + i0) = ((const uint4*)src)[i0 / 8];
    }
}

// ---------------------------------------------------------------------------
// Canonicalize weights (wq|wk|wv|wp -> Wc) and vectors (gw|gb|bq|bk|bv|bp -> Bc).
// ---------------------------------------------------------------------------
__global__ __launch_bounds__(256) void k_cvt_wb(const void* wq, const void* wk,
                                                const void* wv, const void* wp,
                                                const void* gw, const void* gb,
                                                const void* bq, const void* bk,
                                                const void* bv, const void* bp,
                                                const int* __restrict__ flag,
                                                u16* __restrict__ Wc,
                                                u16* __restrict__ Bc) {
    const int mode = *flag;
    int i = blockIdx.x * 256 + threadIdx.x;
    if (i >= 1048576 + 3072) return;
    const void* src;
    u16* dst;
    int off;
    if (i < 1048576) {
        int which = i >> 18;
        off = i & 262143;
        src = which == 0 ? wq : which == 1 ? wk : which == 2 ? wv : wp;
        dst = Wc + i;
    } else {
        int j = i - 1048576;
        int which = j >> 9;
        off = j & 511;
        src = which == 0 ? gw : which == 1 ? gb : which == 2 ? bq
            : which == 3 ? bk : which == 4 ? bv : bp;
        dst = Bc + j;
    }
    *dst = mode ? f2bf(((const float*)src)[off]) : ((const u16*)src)[off];
}

// ---------------------------------------------------------------------------
// 128x128 tile GEMM core: C[M][N] = A[M][K] * BT[N][K]^T, bf16 in, f32 acc.
//   A frag: a[j] = A[m0 + (lane&15)][k0 + (lane>>4)*8 + j]   (m89/m91)
//   B frag: b[j] = BT[n0 + (lane&15)][k0 + (lane>>4)*8 + j]
//   D:      D[m0 + (lane>>4)*4 + r][n0 + (lane&15)]
// Staging: 128 rows x 32 elems = 4096 elems; 256 threads x 16 elems each,
// as TWO uint4 (8 elems each) — uint4 is 8 bf16, not 16 (round-3 fix: the
// old single-uint4 staging left half of every LDS row uninitialized -> NaN).
// ---------------------------------------------------------------------------
__device__ __forceinline__ void gemm_core(const u16* __restrict__ A,
                                          const u16* __restrict__ BT,
                                          int lda, int ldb, int K,
                                          int m0, int n0,
                                          f32x4 (&acc)[4][4]) {
    __shared__ __bf16 lA[128 * LDS_STRIDE];
    __shared__ __bf16 lB[128 * LDS_STRIDE];
    const int t = threadIdx.x;
    const int wave = t >> 6, lane = t & 63;
    const int wm = (wave >> 1) * 64, wn = (wave & 1) * 64;
    const int mf = lane & 15, quad = lane >> 4;
    const int sr = t >> 1;            // staging row 0..127
    const int sk = (t & 1) * 16;      // staging elem offset 0/16
    const u16* Ap = A + (size_t)(m0 + sr) * lda + sk;
    const u16* Bp = BT + (size_t)(n0 + sr) * ldb + sk;

    for (int i = 0; i < 4; i++)
        for (int j = 0; j < 4; j++)
            acc[i][j] = (f32x4){0.f, 0.f, 0.f, 0.f};

    for (int k0 = 0; k0 < K; k0 += 32) {
        uint4 av0 = *(const uint4*)(Ap + k0);
        uint4 av1 = *(const uint4*)(Ap + k0 + 8);
        uint4 bv0 = *(const uint4*)(Bp + k0);
        uint4 bv1 = *(const uint4*)(Bp + k0 + 8);
        __syncthreads();
        *(uint4*)&lA[sr * LDS_STRIDE + sk] = av0;
        *(uint4*)&lA[sr * LDS_STRIDE + sk + 8] = av1;
        *(uint4*)&lB[sr * LDS_STRIDE + sk] = bv0;
        *(uint4*)&lB[sr * LDS_STRIDE + sk + 8] = bv1;
        __syncthreads();
        bf16x8 af[4], bfr[4];
        for (int i = 0; i < 4; i++)
            af[i] = *(const bf16x8*)&lA[(wm + i * 16 + mf) * LDS_STRIDE + quad * 8];
        for (int j = 0; j < 4; j++)
            bfr[j] = *(const bf16x8*)&lB[(wn + j * 16 + mf) * LDS_STRIDE + quad * 8];
        for (int i = 0; i < 4; i++)
            for (int j = 0; j < 4; j++)
                acc[i][j] = __builtin_amdgcn_mfma_f32_16x16x32_bf16(af[i], bfr[j], acc[i][j], 0, 0, 0);
    }
}

// ---------------------------------------------------------------------------
// GroupNorm on canonical bf16 Xc: one block per (batch, group). HT[b][p][c].
// ---------------------------------------------------------------------------
__global__ __launch_bounds__(256) void k_gn(const u16* __restrict__ Xc,
                                            const u16* __restrict__ Bc,
                                            u16* __restrict__ HT) {
    const int b = blockIdx.x >> 5, g = blockIdx.x & 31;
    const u16* base = Xc + (size_t)b * 2097152 + (size_t)g * 65536;
    const uint4* b8 = (const uint4*)base;
    const int t = threadIdx.x;
    const int wave = t >> 6, lane = t & 63;

    float s = 0.f, ss = 0.f;
    for (int it = 0; it < 32; it++) {
        uint4 v = b8[it * 256 + t];
        uint32_t w[4] = {v.x, v.y, v.z, v.w};
        for (int j = 0; j < 4; j++) {
            float a = __uint_as_float(w[j] << 16);
            float bb = __uint_as_float(w[j] & 0xFFFF0000u);
            s += a + bb;
            ss += a * a + bb * bb;
        }
    }
    for (int off = 32; off > 0; off >>= 1) {
        s += __shfl_xor(s, off);
        ss += __shfl_xor(ss, off);
    }
    __shared__ float rs[4], rss[4];
    if (lane == 0) { rs[wave] = s; rss[wave] = ss; }
    __syncthreads();
    s = rs[0] + rs[1] + rs[2] + rs[3];
    ss = rss[0] + rss[1] + rss[2] + rss[3];
    const float mean = s * (1.f / 65536.f);
    const float var = ss * (1.f / 65536.f) - mean * mean;
    const float rstd = rsqrtf(var + 1e-6f);

    __shared__ float csc[16], csh[16];
    if (t < 16) {
        int c = g * 16 + t;
        float w = bf2f(Bc[c]);        // gw
        csc[t] = rstd * w;
        csh[t] = bf2f(Bc[512 + c]) - mean * rstd * w;  // gb
    }
    __syncthreads();

    u16* H = HT + (size_t)b * 2097152;
    for (int it = 0; it < 32; it++) {
        int idx8 = it * 256 + t;
        int idx = idx8 * 8;
        int cl = idx >> 12;
        int p = idx & 4095;
        uint4 v = b8[idx8];
        uint32_t w[4] = {v.x, v.y, v.z, v.w};
        float sc = csc[cl], sh = csh[cl];
        int c = g * 16 + cl;
        u16* o = H + (size_t)p * 512 + c;
        for (int j = 0; j < 4; j++) {
            float a = __uint_as_float(w[j] << 16);
            float bb = __uint_as_float(w[j] & 0xFFFF0000u);
            o[(size_t)(2 * j) * 512] = f2bf(a * sc + sh);
            o[(size_t)(2 * j + 1) * 512] = f2bf(bb * sc + sh);
        }
    }
}

// ---------------------------------------------------------------------------
// QKV: s=0->QT[p][o], 1->KT[p][o], 2->V[o][p]. grid (4, 32, 24)
// ---------------------------------------------------------------------------
__global__ __launch_bounds__(256) void k_qkv(const u16* __restrict__ HT,
                                             const u16* __restrict__ Wc,
                                             const u16* __restrict__ Bc,
                                             u16* __restrict__ QT,
                                             u16* __restrict__ KT,
                                             u16* __restrict__ V) {
    const int n0 = blockIdx.x * 128;
    const int m0 = blockIdx.y * 128;
    const int z = blockIdx.z, b = z / 3, s = z % 3;
    const u16* A = HT + (size_t)b * 2097152;
    const u16* BT = Wc + (size_t)s * 262144;
    const u16* bias = Bc + 1024 + s * 512;   // bq|bk|bv
    f32x4 acc[4][4];
    gemm_core(A, BT, 512, 512, 512, m0, n0, acc);

    const int t = threadIdx.x;
    const int wave = t >> 6, lane = t & 63;
    const int wm = (wave >> 1) * 64, wn = (wave & 1) * 64;
    const int mf = lane & 15, quad = lane >> 4;

    if (s < 2) {
        u16* O = (s == 0 ? QT : KT) + (size_t)b * 2097152;
        for (int i = 0; i < 4; i++)
            for (int r = 0; r < 4; r++) {
                int row = m0 + wm + i * 16 + quad * 4 + r;
                for (int j = 0; j < 4; j++) {
                    int col = n0 + wn + j * 16 + mf;
                    O[(size_t)row * 512 + col] = f2bf(acc[i][j][r] + bf2f(bias[col]));
                }
            }
    } else {
        u16* O = V + (size_t)b * 2097152;
        for (int i = 0; i < 4; i++)
            for (int r = 0; r < 4; r++) {
                int row = m0 + wm + i * 16 + quad * 4 + r;
                for (int j = 0; j < 4; j++) {
                    int col = n0 + wn + j * 16 + mf;
                    O[(size_t)col * 4096 + row] = f2bf(acc[i][j][r] + bf2f(bias[col]));
                }
            }
    }
}

// ---------------------------------------------------------------------------
// Scores: S[q][k'] = (QT @ KT^T) * 512^-0.5. grid (32,32,nb)
// ---------------------------------------------------------------------------
__global__ __launch_bounds__(256) void k_scores(const u16* __restrict__ QT,
                                                const u16* __restrict__ KT,
                                                u16* __restrict__ S) {
    const int n0 = blockIdx.x * 128;
    const int m0 = blockIdx.y * 128;
    const int b = blockIdx.z;
    f32x4 acc[4][4];
    gemm_core(QT + (size_t)b * 2097152, KT + (size_t)b * 2097152, 512, 512, 512, m0, n0, acc);

    const float scale = 0.04419417382415922f;
    const int t = threadIdx.x;
    const int wave = t >> 6, lane = t & 63;
    const int wm = (wave >> 1) * 64, wn = (wave & 1) * 64;
    const int mf = lane & 15, quad = lane >> 4;
    u16* Sb = S + (size_t)b * 16777216;
    for (int i = 0; i < 4; i++)
        for (int r = 0; r < 4; r++) {
            int row = m0 + wm + i * 16 + quad * 4 + r;
            for (int j = 0; j < 4; j++) {
                int col = n0 + wn + j * 16 + mf;
                Sb[(size_t)row * 4096 + col] = f2bf(acc[i][j][r] * scale);
            }
        }
}

// ---------------------------------------------------------------------------
// Softmax over rows of 4096 (in-place, bf16). grid (4096, nb)
// ---------------------------------------------------------------------------
__global__ __launch_bounds__(256) void k_softmax(u16* __restrict__ S) {
    size_t base = ((size_t)blockIdx.y * 4096 + blockIdx.x) * 4096;
    u16* row = S + base;
    const int t = threadIdx.x;
    const int wave = t >> 6, lane = t & 63;

    uint4 v0 = *(const uint4*)(row + t * 16);
    uint4 v1 = *(const uint4*)(row + t * 16 + 8);
    uint32_t w[8] = {v0.x, v0.y, v0.z, v0.w, v1.x, v1.y, v1.z, v1.w};
    float f[16];
    for (int i = 0; i < 8; i++) {
        f[2 * i] = __uint_as_float(w[i] << 16);
        f[2 * i + 1] = __uint_as_float(w[i] & 0xFFFF0000u);
    }
    float m = f[0];
    for (int i = 1; i < 16; i++) m = fmaxf(m, f[i]);
    for (int off = 32; off > 0; off >>= 1) m = fmaxf(m, __shfl_xor(m, off));
    __shared__ float red[4];
    if (lane == 0) red[wave] = m;
    __syncthreads();
    m = fmaxf(fmaxf(red[0], red[1]), fmaxf(red[2], red[3]));

    float s = 0.f;
    for (int i = 0; i < 16; i++) { f[i] = __expf(f[i] - m); s += f[i]; }
    for (int off = 32; off > 0; off >>= 1) s += __shfl_xor(s, off);
    __shared__ float red2[4];
    if (lane == 0) red2[wave] = s;
    __syncthreads();
    s = red2[0] + red2[1] + red2[2] + red2[3];
    const float inv = 1.f / s;

    uint32_t o[8];
    for (int i = 0; i < 8; i++)
        o[i] = (uint32_t)f2bf(f[2 * i] * inv) | ((uint32_t)f2bf(f[2 * i + 1] * inv) << 16);
    *(uint4*)(row + t * 16) = make_uint4(o[0], o[1], o[2], o[3]);
    *(uint4*)(row + t * 16 + 8) = make_uint4(o[4], o[5], o[6], o[7]);
}

// ---------------------------------------------------------------------------
// PV: OT[q][c] = Attn (4096x4096) @ V (512x4096)^T. grid (4, 32, nb)
// ---------------------------------------------------------------------------
__global__ __launch_bounds__(256) void k_pv(const u16* __restrict__ Attn,
                                            const u16* __restrict__ V,
                                            u16* __restrict__ OT) {
    const int n0 = blockIdx.x * 128;
    const int m0 = blockIdx.y * 128;
    const int b = blockIdx.z;
    f32x4 acc[4][4];
    gemm_core(Attn + (size_t)b * 16777216, V + (size_t)b * 2097152, 4096, 4096, 4096, m0, n0, acc);

    const int t = threadIdx.x;
    const int wave = t >> 6, lane = t & 63;
    const int wm = (wave >> 1) * 64, wn = (wave & 1) * 64;
    const int mf = lane & 15, quad = lane >> 4;
    u16* Ob = OT + (size_t)b * 2097152;
    for (int i = 0; i < 4; i++)
        for (int r = 0; r < 4; r++) {
            int row = m0 + wm + i * 16 + quad * 4 + r;
            for (int j = 0; j < 4; j++) {
                int col = n0 + wn + j * 16 + mf;
                Ob[(size_t)row * 512 + col] = f2bf(acc[i][j][r]);
            }
        }
}

// ---------------------------------------------------------------------------
// Proj + residual, dtype-adaptive store: y = Wp @ OT^T + bp + x. grid (32,4,8)
// ---------------------------------------------------------------------------
__global__ __launch_bounds__(256) void k_proj(const u16* __restrict__ Wc,
                                              const u16* __restrict__ OT,
                                              const u16* __restrict__ Bc,
                                              const void* __restrict__ x_raw,
                                              const int* __restrict__ flag,
                                              void* __restrict__ y_raw) {
    const int n0 = blockIdx.x * 128;
    const int m0 = blockIdx.y * 128;
    const int b = blockIdx.z;
    f32x4 acc[4][4];
    gemm_core(Wc + (size_t)3 * 262144, OT + (size_t)b * 2097152, 512, 512, 512, m0, n0, acc);

    const int mode = *flag;
    const u16* bp = Bc + 5 * 512;
    const int t = threadIdx.x;
    const int wave = t >> 6, lane = t & 63;
    const int wm = (wave >> 1) * 64, wn = (wave & 1) * 64;
    const int mf = lane & 15, quad = lane >> 4;
    size_t bb = (size_t)b * 2097152;
    for (int i = 0; i < 4; i++)
        for (int r = 0; r < 4; r++) {
            int row = m0 + wm + i * 16 + quad * 4 + r;
            float brow = bf2f(bp[row]);
            for (int j = 0; j < 4; j++) {
                int col = n0 + wn + j * 16 + mf;
                size_t idx = bb + (size_t)row * 4096 + col;
                float val = acc[i][j][r] + brow;
                if (mode) {
                    ((float*)y_raw)[idx] = val + ((const float*)x_raw)[idx];
                } else {
                    ((u16*)y_raw)[idx] = f2bf(val + bf2f(((const u16*)x_raw)[idx]));
                }
            }
        }
}

// ---------------------------------------------------------------------------
extern "C" void kernel_launch(void* const* d_in, const int* in_sizes, int n_in,
                              void* d_out, int out_size, void* d_ws, size_t ws_size,
                              hipStream_t stream) {
    (void)in_sizes; (void)n_in; (void)out_size;
    const void* x  = d_in[0];
    const void* gw = d_in[1];
    const void* gb = d_in[2];
    const void* wq = d_in[3];
    const void* bq = d_in[4];
    const void* wk = d_in[5];
    const void* bk = d_in[6];
    const void* wv = d_in[7];
    const void* bv = d_in[8];
    const void* wp = d_in[9];
    const void* bp = d_in[10];

    u16* ws16 = (u16*)d_ws;
    int* flag = (int*)d_ws;                 // elems 0..15 reserved
    u16* Xc = ws16 + 16;                    // 16777216 (dead after k_gn)
    u16* Wc = Xc + 16777216;                // 1048576
    u16* Bc = Wc + 1048576;                 // 4096 (6*512 used)
    u16* HT = Bc + 4096;                    // 16777216 (dead after k_qkv)
    u16* QT = HT + 16777216;
    u16* KT = QT + 16777216;
    u16* V  = KT + 16777216;
    u16* Sfull = V + 16777216;              // full mode only: 134217728
    u16* OT = Xc;                           // alias: Xc dead before k_pv

    size_t full_need = 2ull * ((size_t)(Sfull - ws16) + 134217728ull);
    bool full = ws_size >= full_need;

    k_detect<<<1, 256, 0, stream>>>((const u16*)x, flag);
    k_cvt_x<<<8192, 256, 0, stream>>>(x, flag, Xc);
    k_cvt_wb<<<4108, 256, 0, stream>>>(wq, wk, wv, wp, gw, gb, bq, bk, bv, bp,
                                       flag, Wc, Bc);
    k_gn<<<256, 256, 0, stream>>>(Xc, Bc, HT);
    k_qkv<<<dim3(4, 32, 24), 256, 0, stream>>>(HT, Wc, Bc, QT, KT, V);
    if (full) {
        k_scores<<<dim3(32, 32, 8), 256, 0, stream>>>(QT, KT, Sfull);
        k_softmax<<<dim3(4096, 8), 256, 0, stream>>>(Sfull);
        k_pv<<<dim3(4, 32, 8), 256, 0, stream>>>(Sfull, V, OT);
    } else {
        u16* S = HT;   // HT dead after k_qkv
        for (int b = 0; b < 8; b++) {
            k_scores<<<dim3(32, 32, 1), 256, 0, stream>>>(QT + (size_t)b * 2097152,
                                                          KT + (size_t)b * 2097152, S);
            k_softmax<<<dim3(4096, 1), 256, 0, stream>>>(S);
            k_pv<<<dim3(4, 32, 1), 256, 0, stream>>>(S, V + (size_t)b * 2097152,
                                                     OT + (size_t)b * 2097152);
        }
    }
    k_proj<<<dim3(32, 4, 8), 256, 0, stream>>>(Wc, OT, Bc, x, flag, d_out);
}

// Round 5
// 1503.855 us; speedup vs baseline: 1.3042x; 1.3042x over previous
//
#include <hip/hip_runtime.h>
#include <cstdint>

typedef unsigned short u16;
typedef __bf16 bf16x8 __attribute__((ext_vector_type(8)));
typedef float f32x4 __attribute__((ext_vector_type(4)));

__device__ __forceinline__ u16 f2bf(float f) {
    uint32_t u = __float_as_uint(f);
    u += 0x7FFFu + ((u >> 16) & 1u);
    return (u16)(u >> 16);
}
__device__ __forceinline__ float bf2f(u16 v) {
    return __uint_as_float((uint32_t)v << 16);
}

// async global->LDS, 16B per lane (m97: emits global_load_lds_dwordx4)
__device__ __forceinline__ void gload16(const u16* g, u16* l) {
    __builtin_amdgcn_global_load_lds(
        (const __attribute__((address_space(1))) uint32_t*)g,
        (__attribute__((address_space(3))) uint32_t*)l, 16, 0, 0);
}

// ---------------------------------------------------------------------------
// Dtype detect (1=fp32 storage, 0=bf16). fp32 low-mantissa u16 words are
// uniform-random -> max(bits&0x7FFF) ~ 0x7FFF; bf16 N(0,s) stays < 0x5000.
// ---------------------------------------------------------------------------
__global__ __launch_bounds__(256) void k_detect(const u16* __restrict__ x,
                                                int* __restrict__ flag) {
    const int t = threadIdx.x;
    uint32_t mx = 0;
    for (int i = 0; i < 256; i++) {
        uint32_t v = (uint32_t)x[i * 256 + t] & 0x7FFFu;
        mx = mx > v ? mx : v;
    }
    for (int off = 32; off > 0; off >>= 1) {
        uint32_t o = (uint32_t)__shfl_xor((int)mx, off);
        mx = mx > o ? mx : o;
    }
    __shared__ uint32_t r[4];
    if ((t & 63) == 0) r[t >> 6] = mx;
    __syncthreads();
    if (t == 0) {
        uint32_t a = r[0] > r[1] ? r[0] : r[1];
        uint32_t b = r[2] > r[3] ? r[2] : r[3];
        mx = a > b ? a : b;
        *flag = (mx > 0x5000u) ? 1 : 0;
    }
}

// ---------------------------------------------------------------------------
// Canonicalize weights (wq|wk|wv|wp -> Wc) and vectors (gw|gb|bq|bk|bv|bp -> Bc).
// ---------------------------------------------------------------------------
__global__ __launch_bounds__(256) void k_cvt_wb(const void* wq, const void* wk,
                                                const void* wv, const void* wp,
                                                const void* gw, const void* gb,
                                                const void* bq, const void* bk,
                                                const void* bv, const void* bp,
                                                const int* __restrict__ flag,
                                                u16* __restrict__ Wc,
                                                u16* __restrict__ Bc) {
    const int mode = *flag;
    int i = blockIdx.x * 256 + threadIdx.x;
    if (i >= 1048576 + 3072) return;
    const void* src;
    u16* dst;
    int off;
    if (i < 1048576) {
        int which = i >> 18;
        off = i & 262143;
        src = which == 0 ? wq : which == 1 ? wk : which == 2 ? wv : wp;
        dst = Wc + i;
    } else {
        int j = i - 1048576;
        int which = j >> 9;
        off = j & 511;
        src = which == 0 ? gw : which == 1 ? gb : which == 2 ? bq
            : which == 3 ? bk : which == 4 ? bv : bp;
        dst = Bc + j;
    }
    *dst = mode ? f2bf(((const float*)src)[off]) : ((const u16*)src)[off];
}

// ---------------------------------------------------------------------------
// GN stats: one block per (b,g); writes per-channel scale/shift (fp32).
// ---------------------------------------------------------------------------
__global__ __launch_bounds__(256) void k_gn_stats(const void* __restrict__ x_raw,
                                                  const u16* __restrict__ Bc,
                                                  const int* __restrict__ flag,
                                                  float* __restrict__ Sc,
                                                  float* __restrict__ Sh) {
    const int b = blockIdx.x >> 5, g = blockIdx.x & 31;
    const int mode = *flag;
    const int t = threadIdx.x;
    const int wave = t >> 6, lane = t & 63;
    float s = 0.f, ss = 0.f;
    if (mode) {
        const float4* xb = (const float4*)((const float*)x_raw +
                                           ((size_t)b * 512 + g * 16) * 4096);
        for (int it = 0; it < 64; it++) {
            float4 v = xb[it * 256 + t];
            s += v.x + v.y + v.z + v.w;
            ss += v.x * v.x + v.y * v.y + v.z * v.z + v.w * v.w;
        }
    } else {
        const uint4* xb = (const uint4*)((const u16*)x_raw +
                                         ((size_t)b * 512 + g * 16) * 4096);
        for (int it = 0; it < 32; it++) {
            uint4 v = xb[it * 256 + t];
            uint32_t w[4] = {v.x, v.y, v.z, v.w};
            for (int j = 0; j < 4; j++) {
                float a = __uint_as_float(w[j] << 16);
                float c = __uint_as_float(w[j] & 0xFFFF0000u);
                s += a + c;
                ss += a * a + c * c;
            }
        }
    }
    for (int off = 32; off > 0; off >>= 1) {
        s += __shfl_xor(s, off);
        ss += __shfl_xor(ss, off);
    }
    __shared__ float rs[4], rss[4];
    if (lane == 0) { rs[wave] = s; rss[wave] = ss; }
    __syncthreads();
    s = rs[0] + rs[1] + rs[2] + rs[3];
    ss = rss[0] + rss[1] + rss[2] + rss[3];
    const float mean = s * (1.f / 65536.f);
    const float var = ss * (1.f / 65536.f) - mean * mean;
    const float rstd = rsqrtf(var + 1e-6f);
    if (t < 16) {
        int c = g * 16 + t;
        float w = bf2f(Bc[c]);
        Sc[b * 512 + c] = rstd * w;
        Sh[b * 512 + c] = bf2f(Bc[512 + c]) - mean * rstd * w;
    }
}

// ---------------------------------------------------------------------------
// GN apply + transpose: read x[b][c][p0..p0+64) coalesced, LDS transpose,
// write HT[b][p][c] as contiguous 1KB rows. grid (64, 8).
// ---------------------------------------------------------------------------
#define TPAD 520   // 512 + 8: p-row pitch 1040B (16B-aligned for out-reads)
__global__ __launch_bounds__(256) void k_gn_apply(const void* __restrict__ x_raw,
                                                  const int* __restrict__ flag,
                                                  const float* __restrict__ Sc,
                                                  const float* __restrict__ Sh,
                                                  u16* __restrict__ HT) {
    __shared__ u16 tile[64 * TPAD];
    __shared__ float sSc[512], sSh[512];
    const int b = blockIdx.y;
    const int p0 = blockIdx.x * 64;
    const int mode = *flag;
    const int t = threadIdx.x;
    sSc[t] = Sc[b * 512 + t]; sSc[t + 256] = Sc[b * 512 + t + 256];
    sSh[t] = Sh[b * 512 + t]; sSh[t + 256] = Sh[b * 512 + t + 256];
    __syncthreads();
    for (int it = 0; it < 16; it++) {
        int li = it * 256 + t;
        int c = li >> 3;
        int pj = (li & 7) * 8;
        float v[8];
        if (mode) {
            const float* xr = (const float*)x_raw + ((size_t)b * 512 + c) * 4096 + p0 + pj;
            float4 a = *(const float4*)xr;
            float4 d = *(const float4*)(xr + 4);
            v[0] = a.x; v[1] = a.y; v[2] = a.z; v[3] = a.w;
            v[4] = d.x; v[5] = d.y; v[6] = d.z; v[7] = d.w;
        } else {
            const u16* xr = (const u16*)x_raw + ((size_t)b * 512 + c) * 4096 + p0 + pj;
            uint4 a = *(const uint4*)xr;
            uint32_t w[4] = {a.x, a.y, a.z, a.w};
            for (int j = 0; j < 4; j++) {
                v[2 * j] = __uint_as_float(w[j] << 16);
                v[2 * j + 1] = __uint_as_float(w[j] & 0xFFFF0000u);
            }
        }
        float sc = sSc[c], sh = sSh[c];
        for (int k = 0; k < 8; k++)
            tile[(pj + k) * TPAD + c] = f2bf(v[k] * sc + sh);
    }
    __syncthreads();
    u16* H = HT + (size_t)b * 2097152 + (size_t)p0 * 512;
    for (int it = 0; it < 16; it++) {
        int ch = it * 256 + t;
        int pp = ch >> 6;
        int cc = (ch & 63) * 8;
        *(uint4*)&H[(size_t)pp * 512 + cc] = *(const uint4*)&tile[pp * TPAD + cc];
    }
}

// ---------------------------------------------------------------------------
// 128x128 tile GEMM core (m97 structure): C = A[M][K] * BT[N][K]^T.
// Unpadded [128][32] LDS tiles; global_load_lds width-16 staging (the LDS
// dest is wave-uniform base + lane*16, so layout must be raster-contiguous).
//   A frag: a[j] = A[m0 + (lane&15)][k0 + (lane>>4)*8 + j]   (m89/m91)
//   D:      D[m0 + (lane>>4)*4 + r][n0 + (lane&15)]
// ---------------------------------------------------------------------------
__device__ __forceinline__ void gemm_core(const u16* __restrict__ A,
                                          const u16* __restrict__ BT,
                                          int lda, int ldb, int K,
                                          int m0, int n0,
                                          f32x4 (&acc)[4][4]) {
    __shared__ u16 lA[128 * 32];
    __shared__ u16 lB[128 * 32];
    const int t = threadIdx.x;
    const int wave = t >> 6, lane = t & 63;
    const int wm = (wave >> 1) * 64, wn = (wave & 1) * 64;
    const int mf = lane & 15, quad = lane >> 4;
    // staging: chunk ch in [0,512), 16B each; ch = it*256 + t; row=ch>>2, q=ch&3
    const int r0 = t >> 2, q0 = (t & 3) * 8;
    const u16* Ap0 = A + (size_t)(m0 + r0) * lda + q0;
    const u16* Ap1 = A + (size_t)(m0 + 64 + r0) * lda + q0;
    const u16* Bp0 = BT + (size_t)(n0 + r0) * ldb + q0;
    const u16* Bp1 = BT + (size_t)(n0 + 64 + r0) * ldb + q0;
    u16* lA0 = &lA[t * 8];
    u16* lA1 = &lA[(256 + t) * 8];
    u16* lB0 = &lB[t * 8];
    u16* lB1 = &lB[(256 + t) * 8];

    for (int i = 0; i < 4; i++)
        for (int j = 0; j < 4; j++)
            acc[i][j] = (f32x4){0.f, 0.f, 0.f, 0.f};

    for (int k0 = 0; k0 < K; k0 += 32) {
        __syncthreads();
        gload16(Ap0 + k0, lA0);
        gload16(Ap1 + k0, lA1);
        gload16(Bp0 + k0, lB0);
        gload16(Bp1 + k0, lB1);
        __syncthreads();
        bf16x8 af[4], bfr[4];
        for (int i = 0; i < 4; i++)
            af[i] = *(const bf16x8*)&lA[(wm + i * 16 + mf) * 32 + quad * 8];
        for (int j = 0; j < 4; j++)
            bfr[j] = *(const bf16x8*)&lB[(wn + j * 16 + mf) * 32 + quad * 8];
        for (int i = 0; i < 4; i++)
            for (int j = 0; j < 4; j++)
                acc[i][j] = __builtin_amdgcn_mfma_f32_16x16x32_bf16(af[i], bfr[j], acc[i][j], 0, 0, 0);
    }
}

// ---------------------------------------------------------------------------
// QKV: s=0->QT[p][o], 1->KT[p][o], 2->V[o][p]. grid (4, 32, 24)
// ---------------------------------------------------------------------------
__global__ __launch_bounds__(256) void k_qkv(const u16* __restrict__ HT,
                                             const u16* __restrict__ Wc,
                                             const u16* __restrict__ Bc,
                                             u16* __restrict__ QT,
                                             u16* __restrict__ KT,
                                             u16* __restrict__ V) {
    const int n0 = blockIdx.x * 128;
    const int m0 = blockIdx.y * 128;
    const int z = blockIdx.z, b = z / 3, s = z % 3;
    const u16* A = HT + (size_t)b * 2097152;
    const u16* BT = Wc + (size_t)s * 262144;
    const u16* bias = Bc + 1024 + s * 512;   // bq|bk|bv
    f32x4 acc[4][4];
    gemm_core(A, BT, 512, 512, 512, m0, n0, acc);

    const int t = threadIdx.x;
    const int wave = t >> 6, lane = t & 63;
    const int wm = (wave >> 1) * 64, wn = (wave & 1) * 64;
    const int mf = lane & 15, quad = lane >> 4;

    if (s < 2) {
        u16* O = (s == 0 ? QT : KT) + (size_t)b * 2097152;
        for (int i = 0; i < 4; i++)
            for (int r = 0; r < 4; r++) {
                int row = m0 + wm + i * 16 + quad * 4 + r;
                for (int j = 0; j < 4; j++) {
                    int col = n0 + wn + j * 16 + mf;
                    O[(size_t)row * 512 + col] = f2bf(acc[i][j][r] + bf2f(bias[col]));
                }
            }
    } else {
        u16* O = V + (size_t)b * 2097152;
        for (int i = 0; i < 4; i++)
            for (int r = 0; r < 4; r++) {
                int row = m0 + wm + i * 16 + quad * 4 + r;
                for (int j = 0; j < 4; j++) {
                    int col = n0 + wn + j * 16 + mf;
                    O[(size_t)col * 4096 + row] = f2bf(acc[i][j][r] + bf2f(bias[col]));
                }
            }
    }
}

// ---------------------------------------------------------------------------
// Scores: S[q][k'] = (QT @ KT^T) * 512^-0.5. grid (32,32,nb)
// ---------------------------------------------------------------------------
__global__ __launch_bounds__(256) void k_scores(const u16* __restrict__ QT,
                                                const u16* __restrict__ KT,
                                                u16* __restrict__ S) {
    const int n0 = blockIdx.x * 128;
    const int m0 = blockIdx.y * 128;
    const int b = blockIdx.z;
    f32x4 acc[4][4];
    gemm_core(QT + (size_t)b * 2097152, KT + (size_t)b * 2097152, 512, 512, 512, m0, n0, acc);

    const float scale = 0.04419417382415922f;
    const int t = threadIdx.x;
    const int wave = t >> 6, lane = t & 63;
    const int wm = (wave >> 1) * 64, wn = (wave & 1) * 64;
    const int mf = lane & 15, quad = lane >> 4;
    u16* Sb = S + (size_t)b * 16777216;
    for (int i = 0; i < 4; i++)
        for (int r = 0; r < 4; r++) {
            int row = m0 + wm + i * 16 + quad * 4 + r;
            for (int j = 0; j < 4; j++) {
                int col = n0 + wn + j * 16 + mf;
                Sb[(size_t)row * 4096 + col] = f2bf(acc[i][j][r] * scale);
            }
        }
}

// ---------------------------------------------------------------------------
// Softmax over rows of 4096 (in-place, bf16). grid (4096, nb)
// ---------------------------------------------------------------------------
__global__ __launch_bounds__(256) void k_softmax(u16* __restrict__ S) {
    size_t base = ((size_t)blockIdx.y * 4096 + blockIdx.x) * 4096;
    u16* row = S + base;
    const int t = threadIdx.x;
    const int wave = t >> 6, lane = t & 63;

    uint4 v0 = *(const uint4*)(row + t * 16);
    uint4 v1 = *(const uint4*)(row + t * 16 + 8);
    uint32_t w[8] = {v0.x, v0.y, v0.z, v0.w, v1.x, v1.y, v1.z, v1.w};
    float f[16];
    for (int i = 0; i < 8; i++) {
        f[2 * i] = __uint_as_float(w[i] << 16);
        f[2 * i + 1] = __uint_as_float(w[i] & 0xFFFF0000u);
    }
    float m = f[0];
    for (int i = 1; i < 16; i++) m = fmaxf(m, f[i]);
    for (int off = 32; off > 0; off >>= 1) m = fmaxf(m, __shfl_xor(m, off));
    __shared__ float red[4];
    if (lane == 0) red[wave] = m;
    __syncthreads();
    m = fmaxf(fmaxf(red[0], red[1]), fmaxf(red[2], red[3]));

    float s = 0.f;
    for (int i = 0; i < 16; i++) { f[i] = __expf(f[i] - m); s += f[i]; }
    for (int off = 32; off > 0; off >>= 1) s += __shfl_xor(s, off);
    __shared__ float red2[4];
    if (lane == 0) red2[wave] = s;
    __syncthreads();
    s = red2[0] + red2[1] + red2[2] + red2[3];
    const float inv = 1.f / s;

    uint32_t o[8];
    for (int i = 0; i < 8; i++)
        o[i] = (uint32_t)f2bf(f[2 * i] * inv) | ((uint32_t)f2bf(f[2 * i + 1] * inv) << 16);
    *(uint4*)(row + t * 16) = make_uint4(o[0], o[1], o[2], o[3]);
    *(uint4*)(row + t * 16 + 8) = make_uint4(o[4], o[5], o[6], o[7]);
}

// ---------------------------------------------------------------------------
// PV: OT[q][c] = Attn (4096x4096) @ V (512x4096)^T. grid (4, 32, nb)
// ---------------------------------------------------------------------------
__global__ __launch_bounds__(256) void k_pv(const u16* __restrict__ Attn,
                                            const u16* __restrict__ V,
                                            u16* __restrict__ OT) {
    const int n0 = blockIdx.x * 128;
    const int m0 = blockIdx.y * 128;
    const int b = blockIdx.z;
    f32x4 acc[4][4];
    gemm_core(Attn + (size_t)b * 16777216, V + (size_t)b * 2097152, 4096, 4096, 4096, m0, n0, acc);

    const int t = threadIdx.x;
    const int wave = t >> 6, lane = t & 63;
    const int wm = (wave >> 1) * 64, wn = (wave & 1) * 64;
    const int mf = lane & 15, quad = lane >> 4;
    u16* Ob = OT + (size_t)b * 2097152;
    for (int i = 0; i < 4; i++)
        for (int r = 0; r < 4; r++) {
            int row = m0 + wm + i * 16 + quad * 4 + r;
            for (int j = 0; j < 4; j++) {
                int col = n0 + wn + j * 16 + mf;
                Ob[(size_t)row * 512 + col] = f2bf(acc[i][j][r]);
            }
        }
}

// ---------------------------------------------------------------------------
// Proj + residual, dtype-adaptive: y = Wp @ OT^T + bp + x. grid (32,4,8)
// ---------------------------------------------------------------------------
__global__ __launch_bounds__(256) void k_proj(const u16* __restrict__ Wc,
                                              const u16* __restrict__ OT,
                                              const u16* __restrict__ Bc,
                                              const void* __restrict__ x_raw,
                                              const int* __restrict__ flag,
                                              void* __restrict__ y_raw) {
    const int n0 = blockIdx.x * 128;
    const int m0 = blockIdx.y * 128;
    const int b = blockIdx.z;
    f32x4 acc[4][4];
    gemm_core(Wc + (size_t)3 * 262144, OT + (size_t)b * 2097152, 512, 512, 512, m0, n0, acc);

    const int mode = *flag;
    const u16* bp = Bc + 5 * 512;
    const int t = threadIdx.x;
    const int wave = t >> 6, lane = t & 63;
    const int wm = (wave >> 1) * 64, wn = (wave & 1) * 64;
    const int mf = lane & 15, quad = lane >> 4;
    size_t bb = (size_t)b * 2097152;
    for (int i = 0; i < 4; i++)
        for (int r = 0; r < 4; r++) {
            int row = m0 + wm + i * 16 + quad * 4 + r;
            float brow = bf2f(bp[row]);
            for (int j = 0; j < 4; j++) {
                int col = n0 + wn + j * 16 + mf;
                size_t idx = bb + (size_t)row * 4096 + col;
                float val = acc[i][j][r] + brow;
                if (mode) {
                    ((float*)y_raw)[idx] = val + ((const float*)x_raw)[idx];
                } else {
                    ((u16*)y_raw)[idx] = f2bf(val + bf2f(((const u16*)x_raw)[idx]));
                }
            }
        }
}

// ---------------------------------------------------------------------------
extern "C" void kernel_launch(void* const* d_in, const int* in_sizes, int n_in,
                              void* d_out, int out_size, void* d_ws, size_t ws_size,
                              hipStream_t stream) {
    (void)in_sizes; (void)n_in; (void)out_size;
    const void* x  = d_in[0];
    const void* gw = d_in[1];
    const void* gb = d_in[2];
    const void* wq = d_in[3];
    const void* bq = d_in[4];
    const void* wk = d_in[5];
    const void* bk = d_in[6];
    const void* wv = d_in[7];
    const void* bv = d_in[8];
    const void* wp = d_in[9];
    const void* bp = d_in[10];

    u16* ws16 = (u16*)d_ws;
    int* flag = (int*)d_ws;                 // u16 elems 0..15 reserved
    float* Sc = (float*)(ws16 + 16);        // 4096 floats
    float* Sh = Sc + 4096;                  // 4096 floats
    u16* Wc = ws16 + 16 + 16384;            // 1048576
    u16* Bc = Wc + 1048576;                 // 4096 (6*512 used)
    u16* HT = Bc + 4096;                    // 16777216 (dead after k_qkv)
    u16* QT = HT + 16777216;
    u16* KT = QT + 16777216;
    u16* V  = KT + 16777216;
    u16* OT = V  + 16777216;
    u16* Sfull = OT + 16777216;             // full mode only: 134217728

    size_t full_need = 2ull * ((size_t)(Sfull - ws16) + 134217728ull);
    bool full = ws_size >= full_need;

    k_detect<<<1, 256, 0, stream>>>((const u16*)x, flag);
    k_cvt_wb<<<4108, 256, 0, stream>>>(wq, wk, wv, wp, gw, gb, bq, bk, bv, bp,
                                       flag, Wc, Bc);
    k_gn_stats<<<256, 256, 0, stream>>>(x, Bc, flag, Sc, Sh);
    k_gn_apply<<<dim3(64, 8), 256, 0, stream>>>(x, flag, Sc, Sh, HT);
    k_qkv<<<dim3(4, 32, 24), 256, 0, stream>>>(HT, Wc, Bc, QT, KT, V);
    if (full) {
        k_scores<<<dim3(32, 32, 8), 256, 0, stream>>>(QT, KT, Sfull);
        k_softmax<<<dim3(4096, 8), 256, 0, stream>>>(Sfull);
        k_pv<<<dim3(4, 32, 8), 256, 0, stream>>>(Sfull, V, OT);
    } else {
        u16* S = HT;   // HT dead after k_qkv
        for (int b = 0; b < 8; b++) {
            k_scores<<<dim3(32, 32, 1), 256, 0, stream>>>(QT + (size_t)b * 2097152,
                                                          KT + (size_t)b * 2097152, S);
            k_softmax<<<dim3(4096, 1), 256, 0, stream>>>(S);
            k_pv<<<dim3(4, 32, 1), 256, 0, stream>>>(S, V + (size_t)b * 2097152,
                                                     OT + (size_t)b * 2097152);
        }
    }
    k_proj<<<dim3(32, 4, 8), 256, 0, stream>>>(Wc, OT, Bc, x, flag, d_out);
}

// Round 6
// 1009.388 us; speedup vs baseline: 1.9431x; 1.4899x over previous
//
#include <hip/hip_runtime.h>
#include <cstdint>

typedef unsigned short u16;
typedef __bf16 bf16x8 __attribute__((ext_vector_type(8)));
typedef float f32x4 __attribute__((ext_vector_type(4)));

__device__ __forceinline__ u16 f2bf(float f) {
    uint32_t u = __float_as_uint(f);
    u += 0x7FFFu + ((u >> 16) & 1u);
    return (u16)(u >> 16);
}
__device__ __forceinline__ float bf2f(u16 v) {
    return __uint_as_float((uint32_t)v << 16);
}

// async global->LDS, 16B per lane (m97: emits global_load_lds_dwordx4)
__device__ __forceinline__ void gload16(const u16* g, u16* l) {
    __builtin_amdgcn_global_load_lds(
        (const __attribute__((address_space(1))) uint32_t*)g,
        (__attribute__((address_space(3))) uint32_t*)l, 16, 0, 0);
}

// ---------------------------------------------------------------------------
// Dtype detect (1=fp32 storage, 0=bf16).
// ---------------------------------------------------------------------------
__global__ __launch_bounds__(256) void k_detect(const u16* __restrict__ x,
                                                int* __restrict__ flag) {
    const int t = threadIdx.x;
    uint32_t mx = 0;
    for (int i = 0; i < 256; i++) {
        uint32_t v = (uint32_t)x[i * 256 + t] & 0x7FFFu;
        mx = mx > v ? mx : v;
    }
    for (int off = 32; off > 0; off >>= 1) {
        uint32_t o = (uint32_t)__shfl_xor((int)mx, off);
        mx = mx > o ? mx : o;
    }
    __shared__ uint32_t r[4];
    if ((t & 63) == 0) r[t >> 6] = mx;
    __syncthreads();
    if (t == 0) {
        uint32_t a = r[0] > r[1] ? r[0] : r[1];
        uint32_t b = r[2] > r[3] ? r[2] : r[3];
        mx = a > b ? a : b;
        *flag = (mx > 0x5000u) ? 1 : 0;
    }
}

// ---------------------------------------------------------------------------
// Canonicalize weights/vectors into bf16 (Wc: wq|wk|wv|wp, Bc: gw|gb|bq|bk|bv|bp)
// ---------------------------------------------------------------------------
__global__ __launch_bounds__(256) void k_cvt_wb(const void* wq, const void* wk,
                                                const void* wv, const void* wp,
                                                const void* gw, const void* gb,
                                                const void* bq, const void* bk,
                                                const void* bv, const void* bp,
                                                const int* __restrict__ flag,
                                                u16* __restrict__ Wc,
                                                u16* __restrict__ Bc) {
    const int mode = *flag;
    int i = blockIdx.x * 256 + threadIdx.x;
    if (i >= 1048576 + 3072) return;
    const void* src;
    u16* dst;
    int off;
    if (i < 1048576) {
        int which = i >> 18;
        off = i & 262143;
        src = which == 0 ? wq : which == 1 ? wk : which == 2 ? wv : wp;
        dst = Wc + i;
    } else {
        int j = i - 1048576;
        int which = j >> 9;
        off = j & 511;
        src = which == 0 ? gw : which == 1 ? gb : which == 2 ? bq
            : which == 3 ? bk : which == 4 ? bv : bp;
        dst = Bc + j;
    }
    *dst = mode ? f2bf(((const float*)src)[off]) : ((const u16*)src)[off];
}

// ---------------------------------------------------------------------------
// GN stats: one block per (b,g); writes per-channel scale/shift (fp32).
// ---------------------------------------------------------------------------
__global__ __launch_bounds__(256) void k_gn_stats(const void* __restrict__ x_raw,
                                                  const u16* __restrict__ Bc,
                                                  const int* __restrict__ flag,
                                                  float* __restrict__ Sc,
                                                  float* __restrict__ Sh) {
    const int b = blockIdx.x >> 5, g = blockIdx.x & 31;
    const int mode = *flag;
    const int t = threadIdx.x;
    const int wave = t >> 6, lane = t & 63;
    float s = 0.f, ss = 0.f;
    if (mode) {
        const float4* xb = (const float4*)((const float*)x_raw +
                                           ((size_t)b * 512 + g * 16) * 4096);
        for (int it = 0; it < 64; it++) {
            float4 v = xb[it * 256 + t];
            s += v.x + v.y + v.z + v.w;
            ss += v.x * v.x + v.y * v.y + v.z * v.z + v.w * v.w;
        }
    } else {
        const uint4* xb = (const uint4*)((const u16*)x_raw +
                                         ((size_t)b * 512 + g * 16) * 4096);
        for (int it = 0; it < 32; it++) {
            uint4 v = xb[it * 256 + t];
            uint32_t w[4] = {v.x, v.y, v.z, v.w};
            for (int j = 0; j < 4; j++) {
                float a = __uint_as_float(w[j] << 16);
                float c = __uint_as_float(w[j] & 0xFFFF0000u);
                s += a + c;
                ss += a * a + c * c;
            }
        }
    }
    for (int off = 32; off > 0; off >>= 1) {
        s += __shfl_xor(s, off);
        ss += __shfl_xor(ss, off);
    }
    __shared__ float rs[4], rss[4];
    if (lane == 0) { rs[wave] = s; rss[wave] = ss; }
    __syncthreads();
    s = rs[0] + rs[1] + rs[2] + rs[3];
    ss = rss[0] + rss[1] + rss[2] + rss[3];
    const float mean = s * (1.f / 65536.f);
    const float var = ss * (1.f / 65536.f) - mean * mean;
    const float rstd = rsqrtf(var + 1e-6f);
    if (t < 16) {
        int c = g * 16 + t;
        float w = bf2f(Bc[c]);
        Sc[b * 512 + c] = rstd * w;
        Sh[b * 512 + c] = bf2f(Bc[512 + c]) - mean * rstd * w;
    }
}

// ---------------------------------------------------------------------------
// GN apply + transpose -> HT[b][p][c] (contiguous 1KB rows). grid (64, 8).
// ---------------------------------------------------------------------------
#define TPAD 520
__global__ __launch_bounds__(256) void k_gn_apply(const void* __restrict__ x_raw,
                                                  const int* __restrict__ flag,
                                                  const float* __restrict__ Sc,
                                                  const float* __restrict__ Sh,
                                                  u16* __restrict__ HT) {
    __shared__ u16 tile[64 * TPAD];
    __shared__ float sSc[512], sSh[512];
    const int b = blockIdx.y;
    const int p0 = blockIdx.x * 64;
    const int mode = *flag;
    const int t = threadIdx.x;
    sSc[t] = Sc[b * 512 + t]; sSc[t + 256] = Sc[b * 512 + t + 256];
    sSh[t] = Sh[b * 512 + t]; sSh[t + 256] = Sh[b * 512 + t + 256];
    __syncthreads();
    for (int it = 0; it < 16; it++) {
        int li = it * 256 + t;
        int c = li >> 3;
        int pj = (li & 7) * 8;
        float v[8];
        if (mode) {
            const float* xr = (const float*)x_raw + ((size_t)b * 512 + c) * 4096 + p0 + pj;
            float4 a = *(const float4*)xr;
            float4 d = *(const float4*)(xr + 4);
            v[0] = a.x; v[1] = a.y; v[2] = a.z; v[3] = a.w;
            v[4] = d.x; v[5] = d.y; v[6] = d.z; v[7] = d.w;
        } else {
            const u16* xr = (const u16*)x_raw + ((size_t)b * 512 + c) * 4096 + p0 + pj;
            uint4 a = *(const uint4*)xr;
            uint32_t w[4] = {a.x, a.y, a.z, a.w};
            for (int j = 0; j < 4; j++) {
                v[2 * j] = __uint_as_float(w[j] << 16);
                v[2 * j + 1] = __uint_as_float(w[j] & 0xFFFF0000u);
            }
        }
        float sc = sSc[c], sh = sSh[c];
        for (int k = 0; k < 8; k++)
            tile[(pj + k) * TPAD + c] = f2bf(v[k] * sc + sh);
    }
    __syncthreads();
    u16* H = HT + (size_t)b * 2097152 + (size_t)p0 * 512;
    for (int it = 0; it < 16; it++) {
        int ch = it * 256 + t;
        int pp = ch >> 6;
        int cc = (ch & 63) * 8;
        *(uint4*)&H[(size_t)pp * 512 + cc] = *(const uint4*)&tile[pp * TPAD + cc];
    }
}

// ---------------------------------------------------------------------------
// 128x128 tile GEMM core (m97 structure), global_load_lds width-16 staging.
// ---------------------------------------------------------------------------
__device__ __forceinline__ void gemm_core(const u16* __restrict__ A,
                                          const u16* __restrict__ BT,
                                          int lda, int ldb, int K,
                                          int m0, int n0,
                                          f32x4 (&acc)[4][4]) {
    __shared__ u16 lA[128 * 32];
    __shared__ u16 lB[128 * 32];
    const int t = threadIdx.x;
    const int wave = t >> 6, lane = t & 63;
    const int wm = (wave >> 1) * 64, wn = (wave & 1) * 64;
    const int mf = lane & 15, quad = lane >> 4;
    const int r0 = t >> 2, q0 = (t & 3) * 8;
    const u16* Ap0 = A + (size_t)(m0 + r0) * lda + q0;
    const u16* Ap1 = A + (size_t)(m0 + 64 + r0) * lda + q0;
    const u16* Bp0 = BT + (size_t)(n0 + r0) * ldb + q0;
    const u16* Bp1 = BT + (size_t)(n0 + 64 + r0) * ldb + q0;
    u16* lA0 = &lA[t * 8];
    u16* lA1 = &lA[(256 + t) * 8];
    u16* lB0 = &lB[t * 8];
    u16* lB1 = &lB[(256 + t) * 8];

    for (int i = 0; i < 4; i++)
        for (int j = 0; j < 4; j++)
            acc[i][j] = (f32x4){0.f, 0.f, 0.f, 0.f};

    for (int k0 = 0; k0 < K; k0 += 32) {
        __syncthreads();
        gload16(Ap0 + k0, lA0);
        gload16(Ap1 + k0, lA1);
        gload16(Bp0 + k0, lB0);
        gload16(Bp1 + k0, lB1);
        __syncthreads();
        bf16x8 af[4], bfr[4];
        for (int i = 0; i < 4; i++)
            af[i] = *(const bf16x8*)&lA[(wm + i * 16 + mf) * 32 + quad * 8];
        for (int j = 0; j < 4; j++)
            bfr[j] = *(const bf16x8*)&lB[(wn + j * 16 + mf) * 32 + quad * 8];
        for (int i = 0; i < 4; i++)
            for (int j = 0; j < 4; j++)
                acc[i][j] = __builtin_amdgcn_mfma_f32_16x16x32_bf16(af[i], bfr[j], acc[i][j], 0, 0, 0);
    }
}

// ---------------------------------------------------------------------------
// QKV: s=0->QT[p][o], 1->KT[p][o], 2->V[o][p]. grid (4, 32, 24)
// ---------------------------------------------------------------------------
__global__ __launch_bounds__(256) void k_qkv(const u16* __restrict__ HT,
                                             const u16* __restrict__ Wc,
                                             const u16* __restrict__ Bc,
                                             u16* __restrict__ QT,
                                             u16* __restrict__ KT,
                                             u16* __restrict__ V) {
    const int n0 = blockIdx.x * 128;
    const int m0 = blockIdx.y * 128;
    const int z = blockIdx.z, b = z / 3, s = z % 3;
    const u16* A = HT + (size_t)b * 2097152;
    const u16* BT = Wc + (size_t)s * 262144;
    const u16* bias = Bc + 1024 + s * 512;
    f32x4 acc[4][4];
    gemm_core(A, BT, 512, 512, 512, m0, n0, acc);

    const int t = threadIdx.x;
    const int wave = t >> 6, lane = t & 63;
    const int wm = (wave >> 1) * 64, wn = (wave & 1) * 64;
    const int mf = lane & 15, quad = lane >> 4;

    if (s < 2) {
        u16* O = (s == 0 ? QT : KT) + (size_t)b * 2097152;
        for (int i = 0; i < 4; i++)
            for (int r = 0; r < 4; r++) {
                int row = m0 + wm + i * 16 + quad * 4 + r;
                for (int j = 0; j < 4; j++) {
                    int col = n0 + wn + j * 16 + mf;
                    O[(size_t)row * 512 + col] = f2bf(acc[i][j][r] + bf2f(bias[col]));
                }
            }
    } else {
        u16* O = V + (size_t)b * 2097152;
        for (int i = 0; i < 4; i++)
            for (int r = 0; r < 4; r++) {
                int row = m0 + wm + i * 16 + quad * 4 + r;
                for (int j = 0; j < 4; j++) {
                    int col = n0 + wn + j * 16 + mf;
                    O[(size_t)col * 4096 + row] = f2bf(acc[i][j][r] + bf2f(bias[col]));
                }
            }
    }
}

// ---------------------------------------------------------------------------
// Local-batch S pointer: l==0 -> HT region, else tail + (l-1)*16M.
// ---------------------------------------------------------------------------
__device__ __forceinline__ u16* s_ptr(u16* S_ht, u16* S_tail, int l) {
    return l == 0 ? S_ht : S_tail + (size_t)(l - 1) * 16777216;
}

// ---------------------------------------------------------------------------
// Scores: S_l[q][k'] = (QT_b @ KT_b^T) * 512^-0.5. grid (32,32,nb)
// ---------------------------------------------------------------------------
__global__ __launch_bounds__(256) void k_scores(const u16* __restrict__ QT,
                                                const u16* __restrict__ KT,
                                                u16* __restrict__ S_ht,
                                                u16* __restrict__ S_tail,
                                                int b0) {
    const int n0 = blockIdx.x * 128;
    const int m0 = blockIdx.y * 128;
    const int l = blockIdx.z, b = b0 + l;
    f32x4 acc[4][4];
    gemm_core(QT + (size_t)b * 2097152, KT + (size_t)b * 2097152, 512, 512, 512, m0, n0, acc);

    const float scale = 0.04419417382415922f;
    const int t = threadIdx.x;
    const int wave = t >> 6, lane = t & 63;
    const int wm = (wave >> 1) * 64, wn = (wave & 1) * 64;
    const int mf = lane & 15, quad = lane >> 4;
    u16* Sb = s_ptr(S_ht, S_tail, l);
    for (int i = 0; i < 4; i++)
        for (int r = 0; r < 4; r++) {
            int row = m0 + wm + i * 16 + quad * 4 + r;
            for (int j = 0; j < 4; j++) {
                int col = n0 + wn + j * 16 + mf;
                Sb[(size_t)row * 4096 + col] = f2bf(acc[i][j][r] * scale);
            }
        }
}

// ---------------------------------------------------------------------------
// Softmax rows of 4096 in-place. grid (4096, nb)
// ---------------------------------------------------------------------------
__global__ __launch_bounds__(256) void k_softmax(u16* __restrict__ S_ht,
                                                 u16* __restrict__ S_tail) {
    u16* row = s_ptr(S_ht, S_tail, blockIdx.y) + (size_t)blockIdx.x * 4096;
    const int t = threadIdx.x;
    const int wave = t >> 6, lane = t & 63;

    uint4 v0 = *(const uint4*)(row + t * 16);
    uint4 v1 = *(const uint4*)(row + t * 16 + 8);
    uint32_t w[8] = {v0.x, v0.y, v0.z, v0.w, v1.x, v1.y, v1.z, v1.w};
    float f[16];
    for (int i = 0; i < 8; i++) {
        f[2 * i] = __uint_as_float(w[i] << 16);
        f[2 * i + 1] = __uint_as_float(w[i] & 0xFFFF0000u);
    }
    float m = f[0];
    for (int i = 1; i < 16; i++) m = fmaxf(m, f[i]);
    for (int off = 32; off > 0; off >>= 1) m = fmaxf(m, __shfl_xor(m, off));
    __shared__ float red[4];
    if (lane == 0) red[wave] = m;
    __syncthreads();
    m = fmaxf(fmaxf(red[0], red[1]), fmaxf(red[2], red[3]));

    float s = 0.f;
    for (int i = 0; i < 16; i++) { f[i] = __expf(f[i] - m); s += f[i]; }
    for (int off = 32; off > 0; off >>= 1) s += __shfl_xor(s, off);
    __shared__ float red2[4];
    if (lane == 0) red2[wave] = s;
    __syncthreads();
    s = red2[0] + red2[1] + red2[2] + red2[3];
    const float inv = 1.f / s;

    uint32_t o[8];
    for (int i = 0; i < 8; i++)
        o[i] = (uint32_t)f2bf(f[2 * i] * inv) | ((uint32_t)f2bf(f[2 * i + 1] * inv) << 16);
    *(uint4*)(row + t * 16) = make_uint4(o[0], o[1], o[2], o[3]);
    *(uint4*)(row + t * 16 + 8) = make_uint4(o[4], o[5], o[6], o[7]);
}

// ---------------------------------------------------------------------------
// PV split-K=2: partial[split][q][c] over k in [split*2048, +2048).
// Partials (bf16) go into the DEAD QT_b (split 0) / KT_b (split 1) regions.
// grid (4, 32, 2*nb); z = l*2 + split.
// ---------------------------------------------------------------------------
__global__ __launch_bounds__(256) void k_pv_split(u16* __restrict__ S_ht,
                                                  u16* __restrict__ S_tail,
                                                  const u16* __restrict__ V,
                                                  u16* __restrict__ QT,
                                                  u16* __restrict__ KT,
                                                  int b0) {
    const int n0 = blockIdx.x * 128;
    const int m0 = blockIdx.y * 128;
    const int z = blockIdx.z, l = z >> 1, split = z & 1, b = b0 + l;
    const u16* A = s_ptr(S_ht, S_tail, l) + split * 2048;
    const u16* BT = V + (size_t)b * 2097152 + split * 2048;
    f32x4 acc[4][4];
    gemm_core(A, BT, 4096, 4096, 2048, m0, n0, acc);

    const int t = threadIdx.x;
    const int wave = t >> 6, lane = t & 63;
    const int wm = (wave >> 1) * 64, wn = (wave & 1) * 64;
    const int mf = lane & 15, quad = lane >> 4;
    u16* P = (split == 0 ? QT : KT) + (size_t)b * 2097152;
    for (int i = 0; i < 4; i++)
        for (int r = 0; r < 4; r++) {
            int row = m0 + wm + i * 16 + quad * 4 + r;
            for (int j = 0; j < 4; j++) {
                int col = n0 + wn + j * 16 + mf;
                P[(size_t)row * 512 + col] = f2bf(acc[i][j][r]);
            }
        }
}

// ---------------------------------------------------------------------------
// Reduce partials: OT_b = P0 + P1. grid (1024, nb), 8 elems/thread.
// ---------------------------------------------------------------------------
__global__ __launch_bounds__(256) void k_pv_reduce(const u16* __restrict__ QT,
                                                   const u16* __restrict__ KT,
                                                   u16* __restrict__ OT,
                                                   int b0) {
    const int b = b0 + blockIdx.y;
    size_t base = (size_t)b * 2097152;
    size_t i0 = base + ((size_t)blockIdx.x * 256 + threadIdx.x) * 8;
    uint4 a = *(const uint4*)(QT + i0);
    uint4 c = *(const uint4*)(KT + i0);
    uint32_t wa[4] = {a.x, a.y, a.z, a.w};
    uint32_t wc[4] = {c.x, c.y, c.z, c.w};
    uint32_t o[4];
    for (int j = 0; j < 4; j++) {
        float lo = __uint_as_float(wa[j] << 16) + __uint_as_float(wc[j] << 16);
        float hi = __uint_as_float(wa[j] & 0xFFFF0000u) + __uint_as_float(wc[j] & 0xFFFF0000u);
        o[j] = (uint32_t)f2bf(lo) | ((uint32_t)f2bf(hi) << 16);
    }
    *(uint4*)(OT + i0) = make_uint4(o[0], o[1], o[2], o[3]);
}

// ---------------------------------------------------------------------------
// Proj + residual, dtype-adaptive: y = Wp @ OT^T + bp + x. grid (32,4,8)
// ---------------------------------------------------------------------------
__global__ __launch_bounds__(256) void k_proj(const u16* __restrict__ Wc,
                                              const u16* __restrict__ OT,
                                              const u16* __restrict__ Bc,
                                              const void* __restrict__ x_raw,
                                              const int* __restrict__ flag,
                                              void* __restrict__ y_raw) {
    const int n0 = blockIdx.x * 128;
    const int m0 = blockIdx.y * 128;
    const int b = blockIdx.z;
    f32x4 acc[4][4];
    gemm_core(Wc + (size_t)3 * 262144, OT + (size_t)b * 2097152, 512, 512, 512, m0, n0, acc);

    const int mode = *flag;
    const u16* bp = Bc + 5 * 512;
    const int t = threadIdx.x;
    const int wave = t >> 6, lane = t & 63;
    const int wm = (wave >> 1) * 64, wn = (wave & 1) * 64;
    const int mf = lane & 15, quad = lane >> 4;
    size_t bb = (size_t)b * 2097152;
    for (int i = 0; i < 4; i++)
        for (int r = 0; r < 4; r++) {
            int row = m0 + wm + i * 16 + quad * 4 + r;
            float brow = bf2f(bp[row]);
            for (int j = 0; j < 4; j++) {
                int col = n0 + wn + j * 16 + mf;
                size_t idx = bb + (size_t)row * 4096 + col;
                float val = acc[i][j][r] + brow;
                if (mode) {
                    ((float*)y_raw)[idx] = val + ((const float*)x_raw)[idx];
                } else {
                    ((u16*)y_raw)[idx] = f2bf(val + bf2f(((const u16*)x_raw)[idx]));
                }
            }
        }
}

// ---------------------------------------------------------------------------
extern "C" void kernel_launch(void* const* d_in, const int* in_sizes, int n_in,
                              void* d_out, int out_size, void* d_ws, size_t ws_size,
                              hipStream_t stream) {
    (void)in_sizes; (void)n_in; (void)out_size;
    const void* x  = d_in[0];
    const void* gw = d_in[1];
    const void* gb = d_in[2];
    const void* wq = d_in[3];
    const void* bq = d_in[4];
    const void* wk = d_in[5];
    const void* bk = d_in[6];
    const void* wv = d_in[7];
    const void* bv = d_in[8];
    const void* wp = d_in[9];
    const void* bp = d_in[10];

    u16* ws16 = (u16*)d_ws;
    int* flag = (int*)d_ws;                 // u16 elems 0..15
    float* Sc = (float*)(ws16 + 16);        // 4096 f32
    float* Sh = Sc + 4096;                  // 4096 f32
    u16* Wc = ws16 + 16 + 16384;            // 1048576
    u16* Bc = Wc + 1048576;                 // 4096
    u16* HT = Bc + 4096;                    // 16777216 (S slot 0 after qkv)
    u16* QT = HT + 16777216;
    u16* KT = QT + 16777216;
    u16* V  = KT + 16777216;
    u16* OT = V  + 16777216;
    u16* Tail = OT + 16777216;              // S slots 1..nb-1
    const size_t base_elems = (size_t)(Tail - ws16);

    int nb = 1;
    for (int cand = 8; cand >= 2; cand >>= 1) {
        size_t need = 2ull * (base_elems + (size_t)(cand - 1) * 16777216ull);
        if (ws_size >= need) { nb = cand; break; }
    }

    k_detect<<<1, 256, 0, stream>>>((const u16*)x, flag);
    k_cvt_wb<<<4108, 256, 0, stream>>>(wq, wk, wv, wp, gw, gb, bq, bk, bv, bp,
                                       flag, Wc, Bc);
    k_gn_stats<<<256, 256, 0, stream>>>(x, Bc, flag, Sc, Sh);
    k_gn_apply<<<dim3(64, 8), 256, 0, stream>>>(x, flag, Sc, Sh, HT);
    k_qkv<<<dim3(4, 32, 24), 256, 0, stream>>>(HT, Wc, Bc, QT, KT, V);
    for (int b0 = 0; b0 < 8; b0 += nb) {
        k_scores<<<dim3(32, 32, nb), 256, 0, stream>>>(QT, KT, HT, Tail, b0);
        k_softmax<<<dim3(4096, nb), 256, 0, stream>>>(HT, Tail);
        k_pv_split<<<dim3(4, 32, 2 * nb), 256, 0, stream>>>(HT, Tail, V, QT, KT, b0);
        k_pv_reduce<<<dim3(1024, nb), 256, 0, stream>>>(QT, KT, OT, b0);
    }
    k_proj<<<dim3(32, 4, 8), 256, 0, stream>>>(Wc, OT, Bc, x, flag, d_out);
}

// Round 7
// 875.530 us; speedup vs baseline: 2.2402x; 1.1529x over previous
//
#include <hip/hip_runtime.h>
#include <cstdint>

typedef unsigned short u16;
typedef __bf16 bf16x8 __attribute__((ext_vector_type(8)));
typedef float f32x4 __attribute__((ext_vector_type(4)));

__device__ __forceinline__ u16 f2bf(float f) {
    uint32_t u = __float_as_uint(f);
    u += 0x7FFFu + ((u >> 16) & 1u);
    return (u16)(u >> 16);
}
__device__ __forceinline__ float bf2f(u16 v) {
    return __uint_as_float((uint32_t)v << 16);
}

// async global->LDS, 16B per lane (m97: emits global_load_lds_dwordx4)
__device__ __forceinline__ void gload16(const u16* g, u16* l) {
    __builtin_amdgcn_global_load_lds(
        (const __attribute__((address_space(1))) uint32_t*)g,
        (__attribute__((address_space(3))) uint32_t*)l, 16, 0, 0);
}

// XCD-aware work swizzle: blocks sharing an A-tile (same (m,z), all n) get
// lids congruent mod 8 (same XCD heuristic) and within 32 of each other.
__device__ __forceinline__ void swz(int& n_idx, int& m_idx, int& z_idx) {
    const int nx = gridDim.x, ny = gridDim.y;
    int lid = blockIdx.x + nx * (blockIdx.y + ny * blockIdx.z);
    int g = lid & 7, h = lid >> 3;
    n_idx = h % nx;
    int pair = (h / nx) * 8 + g;
    m_idx = pair % ny;
    z_idx = pair / ny;
}

// ---------------------------------------------------------------------------
// Dtype detect (1=fp32 storage, 0=bf16).
// ---------------------------------------------------------------------------
__global__ __launch_bounds__(256) void k_detect(const u16* __restrict__ x,
                                                int* __restrict__ flag) {
    const int t = threadIdx.x;
    uint32_t mx = 0;
    for (int i = 0; i < 256; i++) {
        uint32_t v = (uint32_t)x[i * 256 + t] & 0x7FFFu;
        mx = mx > v ? mx : v;
    }
    for (int off = 32; off > 0; off >>= 1) {
        uint32_t o = (uint32_t)__shfl_xor((int)mx, off);
        mx = mx > o ? mx : o;
    }
    __shared__ uint32_t r[4];
    if ((t & 63) == 0) r[t >> 6] = mx;
    __syncthreads();
    if (t == 0) {
        uint32_t a = r[0] > r[1] ? r[0] : r[1];
        uint32_t b = r[2] > r[3] ? r[2] : r[3];
        mx = a > b ? a : b;
        *flag = (mx > 0x5000u) ? 1 : 0;
    }
}

// ---------------------------------------------------------------------------
// Canonicalize weights/vectors into bf16 (Wc: wq|wk|wv|wp, Bc: gw|gb|bq|bk|bv|bp)
// ---------------------------------------------------------------------------
__global__ __launch_bounds__(256) void k_cvt_wb(const void* wq, const void* wk,
                                                const void* wv, const void* wp,
                                                const void* gw, const void* gb,
                                                const void* bq, const void* bk,
                                                const void* bv, const void* bp,
                                                const int* __restrict__ flag,
                                                u16* __restrict__ Wc,
                                                u16* __restrict__ Bc) {
    const int mode = *flag;
    int i = blockIdx.x * 256 + threadIdx.x;
    if (i >= 1048576 + 3072) return;
    const void* src;
    u16* dst;
    int off;
    if (i < 1048576) {
        int which = i >> 18;
        off = i & 262143;
        src = which == 0 ? wq : which == 1 ? wk : which == 2 ? wv : wp;
        dst = Wc + i;
    } else {
        int j = i - 1048576;
        int which = j >> 9;
        off = j & 511;
        src = which == 0 ? gw : which == 1 ? gb : which == 2 ? bq
            : which == 3 ? bk : which == 4 ? bv : bp;
        dst = Bc + j;
    }
    *dst = mode ? f2bf(((const float*)src)[off]) : ((const u16*)src)[off];
}

// ---------------------------------------------------------------------------
// GN stats: one block per (b,g); writes per-channel scale/shift (fp32).
// ---------------------------------------------------------------------------
__global__ __launch_bounds__(256) void k_gn_stats(const void* __restrict__ x_raw,
                                                  const u16* __restrict__ Bc,
                                                  const int* __restrict__ flag,
                                                  float* __restrict__ Sc,
                                                  float* __restrict__ Sh) {
    const int b = blockIdx.x >> 5, g = blockIdx.x & 31;
    const int mode = *flag;
    const int t = threadIdx.x;
    const int wave = t >> 6, lane = t & 63;
    float s = 0.f, ss = 0.f;
    if (mode) {
        const float4* xb = (const float4*)((const float*)x_raw +
                                           ((size_t)b * 512 + g * 16) * 4096);
        for (int it = 0; it < 64; it++) {
            float4 v = xb[it * 256 + t];
            s += v.x + v.y + v.z + v.w;
            ss += v.x * v.x + v.y * v.y + v.z * v.z + v.w * v.w;
        }
    } else {
        const uint4* xb = (const uint4*)((const u16*)x_raw +
                                         ((size_t)b * 512 + g * 16) * 4096);
        for (int it = 0; it < 32; it++) {
            uint4 v = xb[it * 256 + t];
            uint32_t w[4] = {v.x, v.y, v.z, v.w};
            for (int j = 0; j < 4; j++) {
                float a = __uint_as_float(w[j] << 16);
                float c = __uint_as_float(w[j] & 0xFFFF0000u);
                s += a + c;
                ss += a * a + c * c;
            }
        }
    }
    for (int off = 32; off > 0; off >>= 1) {
        s += __shfl_xor(s, off);
        ss += __shfl_xor(ss, off);
    }
    __shared__ float rs[4], rss[4];
    if (lane == 0) { rs[wave] = s; rss[wave] = ss; }
    __syncthreads();
    s = rs[0] + rs[1] + rs[2] + rs[3];
    ss = rss[0] + rss[1] + rss[2] + rss[3];
    const float mean = s * (1.f / 65536.f);
    const float var = ss * (1.f / 65536.f) - mean * mean;
    const float rstd = rsqrtf(var + 1e-6f);
    if (t < 16) {
        int c = g * 16 + t;
        float w = bf2f(Bc[c]);
        Sc[b * 512 + c] = rstd * w;
        Sh[b * 512 + c] = bf2f(Bc[512 + c]) - mean * rstd * w;
    }
}

// ---------------------------------------------------------------------------
// GN apply + transpose -> HT[b][p][c] (contiguous 1KB rows). grid (64, 8).
// ---------------------------------------------------------------------------
#define TPAD 520
__global__ __launch_bounds__(256) void k_gn_apply(const void* __restrict__ x_raw,
                                                  const int* __restrict__ flag,
                                                  const float* __restrict__ Sc,
                                                  const float* __restrict__ Sh,
                                                  u16* __restrict__ HT) {
    __shared__ u16 tile[64 * TPAD];
    __shared__ float sSc[512], sSh[512];
    const int b = blockIdx.y;
    const int p0 = blockIdx.x * 64;
    const int mode = *flag;
    const int t = threadIdx.x;
    sSc[t] = Sc[b * 512 + t]; sSc[t + 256] = Sc[b * 512 + t + 256];
    sSh[t] = Sh[b * 512 + t]; sSh[t + 256] = Sh[b * 512 + t + 256];
    __syncthreads();
    for (int it = 0; it < 16; it++) {
        int li = it * 256 + t;
        int c = li >> 3;
        int pj = (li & 7) * 8;
        float v[8];
        if (mode) {
            const float* xr = (const float*)x_raw + ((size_t)b * 512 + c) * 4096 + p0 + pj;
            float4 a = *(const float4*)xr;
            float4 d = *(const float4*)(xr + 4);
            v[0] = a.x; v[1] = a.y; v[2] = a.z; v[3] = a.w;
            v[4] = d.x; v[5] = d.y; v[6] = d.z; v[7] = d.w;
        } else {
            const u16* xr = (const u16*)x_raw + ((size_t)b * 512 + c) * 4096 + p0 + pj;
            uint4 a = *(const uint4*)xr;
            uint32_t w[4] = {a.x, a.y, a.z, a.w};
            for (int j = 0; j < 4; j++) {
                v[2 * j] = __uint_as_float(w[j] << 16);
                v[2 * j + 1] = __uint_as_float(w[j] & 0xFFFF0000u);
            }
        }
        float sc = sSc[c], sh = sSh[c];
        for (int k = 0; k < 8; k++)
            tile[(pj + k) * TPAD + c] = f2bf(v[k] * sc + sh);
    }
    __syncthreads();
    u16* H = HT + (size_t)b * 2097152 + (size_t)p0 * 512;
    for (int it = 0; it < 16; it++) {
        int ch = it * 256 + t;
        int pp = ch >> 6;
        int cc = (ch & 63) * 8;
        *(uint4*)&H[(size_t)pp * 512 + cc] = *(const uint4*)&tile[pp * TPAD + cc];
    }
}

// ---------------------------------------------------------------------------
// 128x128 tile GEMM core, BK=64 (2 MFMA K-steps per barrier pair).
// LDS layout XOR-swizzled: LDS slot (row, s) holds global chunk
// col8 = s ^ (row&7); fragment reads then hit all 32 banks per 8-lane phase
// (conflict-free) while keeping the raster-contiguous LDS dest that
// global_load_lds requires. K must be a multiple of 64.
// ---------------------------------------------------------------------------
__device__ __forceinline__ void gemm_core(const u16* __restrict__ A,
                                          const u16* __restrict__ BT,
                                          int lda, int ldb, int K,
                                          int m0, int n0,
                                          f32x4 (&acc)[4][4]) {
    __shared__ u16 lA[128 * 64];
    __shared__ u16 lB[128 * 64];
    const int t = threadIdx.x;
    const int wave = t >> 6, lane = t & 63;
    const int wm = (wave >> 1) * 64, wn = (wave & 1) * 64;
    const int mf = lane & 15, quad = lane >> 4;
    // staging: thread t covers LDS chunks t, t+256, t+512, t+768 (rows +32)
    const int srow = t >> 3;                        // 0..31
    const int scol = (((t & 7) ^ (srow & 7)) * 8);  // global col elems (XOR swz)
    const u16* Ap = A + (size_t)(m0 + srow) * lda + scol;
    const u16* Bp = BT + (size_t)(n0 + srow) * ldb + scol;
    u16* lAd = &lA[t * 8];
    u16* lBd = &lB[t * 8];
    const int fx = mf & 7;   // fragment slot XOR key (per-lane static)

    for (int i = 0; i < 4; i++)
        for (int j = 0; j < 4; j++)
            acc[i][j] = (f32x4){0.f, 0.f, 0.f, 0.f};

    for (int k0 = 0; k0 < K; k0 += 64) {
        __syncthreads();
        gload16(Ap + k0, lAd);
        gload16(Ap + k0 + (size_t)32 * lda, lAd + 2048);
        gload16(Ap + k0 + (size_t)64 * lda, lAd + 4096);
        gload16(Ap + k0 + (size_t)96 * lda, lAd + 6144);
        gload16(Bp + k0, lBd);
        gload16(Bp + k0 + (size_t)32 * ldb, lBd + 2048);
        gload16(Bp + k0 + (size_t)64 * ldb, lBd + 4096);
        gload16(Bp + k0 + (size_t)96 * ldb, lBd + 6144);
        __syncthreads();
        for (int ks = 0; ks < 2; ks++) {
            bf16x8 af[4], bfr[4];
            const int sl = ((ks * 4 + quad) ^ fx) * 8;
            for (int i = 0; i < 4; i++)
                af[i] = *(const bf16x8*)&lA[(wm + i * 16 + mf) * 64 + sl];
            for (int j = 0; j < 4; j++)
                bfr[j] = *(const bf16x8*)&lB[(wn + j * 16 + mf) * 64 + sl];
            for (int i = 0; i < 4; i++)
                for (int j = 0; j < 4; j++)
                    acc[i][j] = __builtin_amdgcn_mfma_f32_16x16x32_bf16(af[i], bfr[j], acc[i][j], 0, 0, 0);
        }
    }
}

// ---------------------------------------------------------------------------
// QKV: s=0->QT[p][o], 1->KT[p][o], 2->V[o][p]. grid (4, 32, 24)
// ---------------------------------------------------------------------------
__global__ __launch_bounds__(256) void k_qkv(const u16* __restrict__ HT,
                                             const u16* __restrict__ Wc,
                                             const u16* __restrict__ Bc,
                                             u16* __restrict__ QT,
                                             u16* __restrict__ KT,
                                             u16* __restrict__ V) {
    int nI, mI, zI;
    swz(nI, mI, zI);
    const int n0 = nI * 128;
    const int m0 = mI * 128;
    const int b = zI / 3, s = zI % 3;
    const u16* A = HT + (size_t)b * 2097152;
    const u16* BT = Wc + (size_t)s * 262144;
    const u16* bias = Bc + 1024 + s * 512;
    f32x4 acc[4][4];
    gemm_core(A, BT, 512, 512, 512, m0, n0, acc);

    const int t = threadIdx.x;
    const int wave = t >> 6, lane = t & 63;
    const int wm = (wave >> 1) * 64, wn = (wave & 1) * 64;
    const int mf = lane & 15, quad = lane >> 4;

    if (s < 2) {
        u16* O = (s == 0 ? QT : KT) + (size_t)b * 2097152;
        for (int i = 0; i < 4; i++)
            for (int r = 0; r < 4; r++) {
                int row = m0 + wm + i * 16 + quad * 4 + r;
                for (int j = 0; j < 4; j++) {
                    int col = n0 + wn + j * 16 + mf;
                    O[(size_t)row * 512 + col] = f2bf(acc[i][j][r] + bf2f(bias[col]));
                }
            }
    } else {
        u16* O = V + (size_t)b * 2097152;
        for (int i = 0; i < 4; i++)
            for (int r = 0; r < 4; r++) {
                int row = m0 + wm + i * 16 + quad * 4 + r;
                for (int j = 0; j < 4; j++) {
                    int col = n0 + wn + j * 16 + mf;
                    O[(size_t)col * 4096 + row] = f2bf(acc[i][j][r] + bf2f(bias[col]));
                }
            }
    }
}

// ---------------------------------------------------------------------------
// Local-batch S pointer: l==0 -> HT region, else tail + (l-1)*16M.
// ---------------------------------------------------------------------------
__device__ __forceinline__ u16* s_ptr(u16* S_ht, u16* S_tail, int l) {
    return l == 0 ? S_ht : S_tail + (size_t)(l - 1) * 16777216;
}

// ---------------------------------------------------------------------------
// Scores: S_l[q][k'] = (QT_b @ KT_b^T) * 512^-0.5. grid (32,32,nb)
// ---------------------------------------------------------------------------
__global__ __launch_bounds__(256) void k_scores(const u16* __restrict__ QT,
                                                const u16* __restrict__ KT,
                                                u16* __restrict__ S_ht,
                                                u16* __restrict__ S_tail,
                                                int b0) {
    int nI, mI, l;
    swz(nI, mI, l);
    const int n0 = nI * 128;
    const int m0 = mI * 128;
    const int b = b0 + l;
    f32x4 acc[4][4];
    gemm_core(QT + (size_t)b * 2097152, KT + (size_t)b * 2097152, 512, 512, 512, m0, n0, acc);

    const float scale = 0.04419417382415922f;
    const int t = threadIdx.x;
    const int wave = t >> 6, lane = t & 63;
    const int wm = (wave >> 1) * 64, wn = (wave & 1) * 64;
    const int mf = lane & 15, quad = lane >> 4;
    u16* Sb = s_ptr(S_ht, S_tail, l);
    for (int i = 0; i < 4; i++)
        for (int r = 0; r < 4; r++) {
            int row = m0 + wm + i * 16 + quad * 4 + r;
            for (int j = 0; j < 4; j++) {
                int col = n0 + wn + j * 16 + mf;
                Sb[(size_t)row * 4096 + col] = f2bf(acc[i][j][r] * scale);
            }
        }
}

// ---------------------------------------------------------------------------
// Softmax rows of 4096 in-place. grid (4096, nb)
// ---------------------------------------------------------------------------
__global__ __launch_bounds__(256) void k_softmax(u16* __restrict__ S_ht,
                                                 u16* __restrict__ S_tail) {
    u16* row = s_ptr(S_ht, S_tail, blockIdx.y) + (size_t)blockIdx.x * 4096;
    const int t = threadIdx.x;
    const int wave = t >> 6, lane = t & 63;

    uint4 v0 = *(const uint4*)(row + t * 16);
    uint4 v1 = *(const uint4*)(row + t * 16 + 8);
    uint32_t w[8] = {v0.x, v0.y, v0.z, v0.w, v1.x, v1.y, v1.z, v1.w};
    float f[16];
    for (int i = 0; i < 8; i++) {
        f[2 * i] = __uint_as_float(w[i] << 16);
        f[2 * i + 1] = __uint_as_float(w[i] & 0xFFFF0000u);
    }
    float m = f[0];
    for (int i = 1; i < 16; i++) m = fmaxf(m, f[i]);
    for (int off = 32; off > 0; off >>= 1) m = fmaxf(m, __shfl_xor(m, off));
    __shared__ float red[4];
    if (lane == 0) red[wave] = m;
    __syncthreads();
    m = fmaxf(fmaxf(red[0], red[1]), fmaxf(red[2], red[3]));

    float s = 0.f;
    for (int i = 0; i < 16; i++) { f[i] = __expf(f[i] - m); s += f[i]; }
    for (int off = 32; off > 0; off >>= 1) s += __shfl_xor(s, off);
    __shared__ float red2[4];
    if (lane == 0) red2[wave] = s;
    __syncthreads();
    s = red2[0] + red2[1] + red2[2] + red2[3];
    const float inv = 1.f / s;

    uint32_t o[8];
    for (int i = 0; i < 8; i++)
        o[i] = (uint32_t)f2bf(f[2 * i] * inv) | ((uint32_t)f2bf(f[2 * i + 1] * inv) << 16);
    *(uint4*)(row + t * 16) = make_uint4(o[0], o[1], o[2], o[3]);
    *(uint4*)(row + t * 16 + 8) = make_uint4(o[4], o[5], o[6], o[7]);
}

// ---------------------------------------------------------------------------
// PV split-K=2: partials into dead QT_b / KT_b regions. grid (4, 32, 2*nb)
// ---------------------------------------------------------------------------
__global__ __launch_bounds__(256) void k_pv_split(u16* __restrict__ S_ht,
                                                  u16* __restrict__ S_tail,
                                                  const u16* __restrict__ V,
                                                  u16* __restrict__ QT,
                                                  u16* __restrict__ KT,
                                                  int b0) {
    int nI, mI, zI;
    swz(nI, mI, zI);
    const int n0 = nI * 128;
    const int m0 = mI * 128;
    const int l = zI >> 1, split = zI & 1, b = b0 + l;
    const u16* A = s_ptr(S_ht, S_tail, l) + split * 2048;
    const u16* BT = V + (size_t)b * 2097152 + split * 2048;
    f32x4 acc[4][4];
    gemm_core(A, BT, 4096, 4096, 2048, m0, n0, acc);

    const int t = threadIdx.x;
    const int wave = t >> 6, lane = t & 63;
    const int wm = (wave >> 1) * 64, wn = (wave & 1) * 64;
    const int mf = lane & 15, quad = lane >> 4;
    u16* P = (split == 0 ? QT : KT) + (size_t)b * 2097152;
    for (int i = 0; i < 4; i++)
        for (int r = 0; r < 4; r++) {
            int row = m0 + wm + i * 16 + quad * 4 + r;
            for (int j = 0; j < 4; j++) {
                int col = n0 + wn + j * 16 + mf;
                P[(size_t)row * 512 + col] = f2bf(acc[i][j][r]);
            }
        }
}

// ---------------------------------------------------------------------------
// Reduce partials: OT_b = P0 + P1. grid (1024, nb), 8 elems/thread.
// ---------------------------------------------------------------------------
__global__ __launch_bounds__(256) void k_pv_reduce(const u16* __restrict__ QT,
                                                   const u16* __restrict__ KT,
                                                   u16* __restrict__ OT,
                                                   int b0) {
    const int b = b0 + blockIdx.y;
    size_t base = (size_t)b * 2097152;
    size_t i0 = base + ((size_t)blockIdx.x * 256 + threadIdx.x) * 8;
    uint4 a = *(const uint4*)(QT + i0);
    uint4 c = *(const uint4*)(KT + i0);
    uint32_t wa[4] = {a.x, a.y, a.z, a.w};
    uint32_t wc[4] = {c.x, c.y, c.z, c.w};
    uint32_t o[4];
    for (int j = 0; j < 4; j++) {
        float lo = __uint_as_float(wa[j] << 16) + __uint_as_float(wc[j] << 16);
        float hi = __uint_as_float(wa[j] & 0xFFFF0000u) + __uint_as_float(wc[j] & 0xFFFF0000u);
        o[j] = (uint32_t)f2bf(lo) | ((uint32_t)f2bf(hi) << 16);
    }
    *(uint4*)(OT + i0) = make_uint4(o[0], o[1], o[2], o[3]);
}

// ---------------------------------------------------------------------------
// Proj + residual, dtype-adaptive: y = Wp @ OT^T + bp + x. grid (32,4,8)
// ---------------------------------------------------------------------------
__global__ __launch_bounds__(256) void k_proj(const u16* __restrict__ Wc,
                                              const u16* __restrict__ OT,
                                              const u16* __restrict__ Bc,
                                              const void* __restrict__ x_raw,
                                              const int* __restrict__ flag,
                                              void* __restrict__ y_raw) {
    int nI, mI, b;
    swz(nI, mI, b);
    const int n0 = nI * 128;
    const int m0 = mI * 128;
    f32x4 acc[4][4];
    gemm_core(Wc + (size_t)3 * 262144, OT + (size_t)b * 2097152, 512, 512, 512, m0, n0, acc);

    const int mode = *flag;
    const u16* bp = Bc + 5 * 512;
    const int t = threadIdx.x;
    const int wave = t >> 6, lane = t & 63;
    const int wm = (wave >> 1) * 64, wn = (wave & 1) * 64;
    const int mf = lane & 15, quad = lane >> 4;
    size_t bb = (size_t)b * 2097152;
    for (int i = 0; i < 4; i++)
        for (int r = 0; r < 4; r++) {
            int row = m0 + wm + i * 16 + quad * 4 + r;
            float brow = bf2f(bp[row]);
            for (int j = 0; j < 4; j++) {
                int col = n0 + wn + j * 16 + mf;
                size_t idx = bb + (size_t)row * 4096 + col;
                float val = acc[i][j][r] + brow;
                if (mode) {
                    ((float*)y_raw)[idx] = val + ((const float*)x_raw)[idx];
                } else {
                    ((u16*)y_raw)[idx] = f2bf(val + bf2f(((const u16*)x_raw)[idx]));
                }
            }
        }
}

// ---------------------------------------------------------------------------
extern "C" void kernel_launch(void* const* d_in, const int* in_sizes, int n_in,
                              void* d_out, int out_size, void* d_ws, size_t ws_size,
                              hipStream_t stream) {
    (void)in_sizes; (void)n_in; (void)out_size;
    const void* x  = d_in[0];
    const void* gw = d_in[1];
    const void* gb = d_in[2];
    const void* wq = d_in[3];
    const void* bq = d_in[4];
    const void* wk = d_in[5];
    const void* bk = d_in[6];
    const void* wv = d_in[7];
    const void* bv = d_in[8];
    const void* wp = d_in[9];
    const void* bp = d_in[10];

    u16* ws16 = (u16*)d_ws;
    int* flag = (int*)d_ws;                 // u16 elems 0..15
    float* Sc = (float*)(ws16 + 16);        // 4096 f32
    float* Sh = Sc + 4096;                  // 4096 f32
    u16* Wc = ws16 + 16 + 16384;            // 1048576
    u16* Bc = Wc + 1048576;                 // 4096
    u16* HT = Bc + 4096;                    // 16777216 (S slot 0 after qkv)
    u16* QT = HT + 16777216;
    u16* KT = QT + 16777216;
    u16* V  = KT + 16777216;
    u16* OT = V  + 16777216;
    u16* Tail = OT + 16777216;              // S slots 1..nb-1
    const size_t base_elems = (size_t)(Tail - ws16);

    int nb = 1;
    for (int cand = 8; cand >= 2; cand >>= 1) {
        size_t need = 2ull * (base_elems + (size_t)(cand - 1) * 16777216ull);
        if (ws_size >= need) { nb = cand; break; }
    }

    k_detect<<<1, 256, 0, stream>>>((const u16*)x, flag);
    k_cvt_wb<<<4108, 256, 0, stream>>>(wq, wk, wv, wp, gw, gb, bq, bk, bv, bp,
                                       flag, Wc, Bc);
    k_gn_stats<<<256, 256, 0, stream>>>(x, Bc, flag, Sc, Sh);
    k_gn_apply<<<dim3(64, 8), 256, 0, stream>>>(x, flag, Sc, Sh, HT);
    k_qkv<<<dim3(4, 32, 24), 256, 0, stream>>>(HT, Wc, Bc, QT, KT, V);
    for (int b0 = 0; b0 < 8; b0 += nb) {
        k_scores<<<dim3(32, 32, nb), 256, 0, stream>>>(QT, KT, HT, Tail, b0);
        k_softmax<<<dim3(4096, nb), 256, 0, stream>>>(HT, Tail);
        k_pv_split<<<dim3(4, 32, 2 * nb), 256, 0, stream>>>(HT, Tail, V, QT, KT, b0);
        k_pv_reduce<<<dim3(1024, nb), 256, 0, stream>>>(QT, KT, OT, b0);
    }
    k_proj<<<dim3(32, 4, 8), 256, 0, stream>>>(Wc, OT, Bc, x, flag, d_out);
}